// Round 3
// 1108.108 us; speedup vs baseline: 1.1710x; 1.1710x over previous
//
#include <hip/hip_runtime.h>
#include <hip/hip_bf16.h>

#define IN_F 128
#define OUT_F 64

typedef __hip_bfloat16 bf16;
typedef __attribute__((ext_vector_type(8))) short short8;
typedef __attribute__((ext_vector_type(4))) float f32x4;

// ---------------- problem constants (all compile-time) ----------------
#define N_AUTHOR 100000
#define N_PAPER  200000
#define N_FIELD  50000
#define N_INST   8000
#define N_NODES  858000
#define E_TOTAL  5000000

// output segment bases (floats)
#define OUT_AUTHOR 0L
#define OUT_FIELD  (6400000L)     // N_AUTHOR*64
#define OUT_INST   (9600000L)     // + N_FIELD*64
#define OUT_PAPER  (10112000L)    // + N_INST*64

// deg/off segment bases (per destination of each relation)
#define DG_WRITES   0
#define DG_RWRITES  200000
#define DG_CITES    300000
#define DG_HTOPIC   500000
#define DG_RHTOPIC  550000
#define DG_AFFIL    750000
#define DG_RAFFIL   758000

// y-table row bases (per relation)
#define YR_WRITES   0L
#define YR_RWRITES  100000L
#define YR_CITES    300000L
#define YR_HTOPIC   500000L
#define YR_RHTOPIC  700000L
#define YR_AFFIL    750000L
#define YR_RAFFIL   850000L

__device__ inline short f2bf(float f) {
    __hip_bfloat16 h = __float2bfloat16(f);
    return __builtin_bit_cast(short, h);
}
__device__ inline float bflo(unsigned u) {
    unsigned v = u << 16;
    return __builtin_bit_cast(float, v);
}
__device__ inline float bfhi(unsigned u) {
    unsigned v = u & 0xFFFF0000u;
    return __builtin_bit_cast(float, v);
}

// ============ XCD-sliced degree count ============
// Each relation's dst-node range is split into 8 equal slices; a block only
// counts edges whose dst falls in its slice (slice = blockIdx&7 -> XCD via
// round-robin dispatch). Per-XCD atomic working set = n_dst/8 ints -> stays
// resident in that XCD's private L2. Edge lists are rescanned 8x but those
// reads are sequential + L3-resident (edge data 40 MB << 256 MB L3).
// Chunks of 2048 edges/block, int4 loads (4 edges/thread x 2 iters).
__device__ __forceinline__ void degSegS(const int* __restrict__ dst, int E,
                                        int* __restrict__ deg, int chunk,
                                        int lo, int wid) {
    const int base = chunk * 2048 + (int)threadIdx.x * 4;
    #pragma unroll
    for (int it = 0; it < 2; it++) {
        int i = base + it * 1024;
        if (i + 3 < E) {
            int4 d = *(const int4*)(dst + i);
            if ((unsigned)(d.x - lo) < (unsigned)wid) atomicAdd(&deg[d.x], 1);
            if ((unsigned)(d.y - lo) < (unsigned)wid) atomicAdd(&deg[d.y], 1);
            if ((unsigned)(d.z - lo) < (unsigned)wid) atomicAdd(&deg[d.z], 1);
            if ((unsigned)(d.w - lo) < (unsigned)wid) atomicAdd(&deg[d.w], 1);
        } else {
            for (int k = 0; k < 4; k++) {
                int ii = i + k;
                if (ii < E) {
                    int dd = dst[ii];
                    if ((unsigned)(dd - lo) < (unsigned)wid) atomicAdd(&deg[dd], 1);
                }
            }
        }
    }
}

// chunk counts: 1M->489, 800k->391, 200k->98 ; per-slice total 2445; grid 19560
__global__ __launch_bounds__(256) void deg_all(
    const int* d0, const int* d1, const int* d2, const int* d3,
    const int* d4, const int* d5, const int* d6, int* __restrict__ deg) {
    const int b = blockIdx.x;
    const int s = b & 7;         // slice -> XCD (round-robin dispatch)
    const int t = b >> 3;
    if      (t < 489)  degSegS(d0, 1000000, deg + DG_WRITES,  t,        s * 25000, 25000);
    else if (t < 978)  degSegS(d1, 1000000, deg + DG_RWRITES, t - 489,  s * 12500, 12500);
    else if (t < 1467) degSegS(d2, 1000000, deg + DG_CITES,   t - 978,  s * 25000, 25000);
    else if (t < 1858) degSegS(d3,  800000, deg + DG_HTOPIC,  t - 1467, s * 6250,  6250);
    else if (t < 2249) degSegS(d4,  800000, deg + DG_RHTOPIC, t - 1858, s * 25000, 25000);
    else if (t < 2347) degSegS(d5,  200000, deg + DG_AFFIL,   t - 2249, s * 1000,  1000);
    else               degSegS(d6,  200000, deg + DG_RAFFIL,  t - 2347, s * 12500, 12500);
}

// ================= 3-phase exclusive scan =================
__global__ __launch_bounds__(256) void scan1(const int* __restrict__ deg,
                                             int* __restrict__ off,
                                             int* __restrict__ bsums, int n) {
    __shared__ int ts[256];
    const int tid = threadIdx.x;
    const int base = blockIdx.x * 1024 + tid * 4;
    int4 v = {0, 0, 0, 0};
    if (base < n) v = *(const int4*)(deg + base);
    int sum = v.x + v.y + v.z + v.w;
    ts[tid] = sum;
    __syncthreads();
    for (int o = 1; o < 256; o <<= 1) {
        int t = (tid >= o) ? ts[tid - o] : 0;
        __syncthreads();
        ts[tid] += t;
        __syncthreads();
    }
    int pre = ts[tid] - sum;
    if (base < n) {
        int4 e;
        e.x = pre;
        e.y = pre + v.x;
        e.z = pre + v.x + v.y;
        e.w = pre + v.x + v.y + v.z;
        *(int4*)(off + base) = e;
    }
    if (tid == 255) bsums[blockIdx.x] = ts[255];
}

__global__ __launch_bounds__(1024) void scan2(int* __restrict__ bsums, int nb) {
    __shared__ int ts[1024];
    const int tid = threadIdx.x;
    int v = (tid < nb) ? bsums[tid] : 0;
    ts[tid] = v;
    __syncthreads();
    for (int o = 1; o < 1024; o <<= 1) {
        int t = (tid >= o) ? ts[tid - o] : 0;
        __syncthreads();
        ts[tid] += t;
        __syncthreads();
    }
    if (tid < nb) bsums[tid] = ts[tid] - v;
}

__global__ __launch_bounds__(256) void scan3(int* __restrict__ off,
                                             int* __restrict__ cursor,
                                             const int* __restrict__ bsums,
                                             int n, int e_total) {
    const int tid = threadIdx.x;
    const int base = blockIdx.x * 1024 + tid * 4;
    const int bp = bsums[blockIdx.x];
    if (base < n) {
        int4 v = *(const int4*)(off + base);
        v.x += bp; v.y += bp; v.z += bp; v.w += bp;
        *(int4*)(off + base) = v;
        *(int4*)(cursor + base) = v;
    }
    if (blockIdx.x == 0 && tid == 0) off[n] = e_total;
}

// ============ XCD-sliced CSR fill ============
// Same slicing as deg_all: each XCD's csr write region is ~2.5 MB (20 MB / 8)
// + ~0.43 MB of cursor entries -> fits its private 4 MiB L2, so the 4 B
// scattered stores accumulate ~16 per line before a single writeback instead
// of thrashing (was: WRITE_SIZE 343 MB for a 20 MB csr).
__device__ __forceinline__ void fillSegS(const int* __restrict__ src,
                                         const int* __restrict__ dst, int E,
                                         int* __restrict__ cursor,
                                         int* __restrict__ csr, int chunk,
                                         int lo, int wid) {
    const int base = chunk * 2048 + (int)threadIdx.x * 4;
    #pragma unroll
    for (int it = 0; it < 2; it++) {
        int i = base + it * 1024;
        if (i + 3 < E) {
            int4 d = *(const int4*)(dst + i);
            int4 sv = *(const int4*)(src + i);
            if ((unsigned)(d.x - lo) < (unsigned)wid) { int p = atomicAdd(&cursor[d.x], 1); csr[p] = sv.x; }
            if ((unsigned)(d.y - lo) < (unsigned)wid) { int p = atomicAdd(&cursor[d.y], 1); csr[p] = sv.y; }
            if ((unsigned)(d.z - lo) < (unsigned)wid) { int p = atomicAdd(&cursor[d.z], 1); csr[p] = sv.z; }
            if ((unsigned)(d.w - lo) < (unsigned)wid) { int p = atomicAdd(&cursor[d.w], 1); csr[p] = sv.w; }
        } else {
            for (int k = 0; k < 4; k++) {
                int ii = i + k;
                if (ii < E) {
                    int dd = dst[ii];
                    if ((unsigned)(dd - lo) < (unsigned)wid) {
                        int p = atomicAdd(&cursor[dd], 1);
                        csr[p] = src[ii];
                    }
                }
            }
        }
    }
}

__global__ __launch_bounds__(256) void fill_all(
    const int* s0, const int* d0, const int* s1, const int* d1,
    const int* s2, const int* d2, const int* s3, const int* d3,
    const int* s4, const int* d4, const int* s5, const int* d5,
    const int* s6, const int* d6,
    int* __restrict__ cursor, int* __restrict__ csr) {
    const int b = blockIdx.x;
    const int s = b & 7;         // slice -> XCD (round-robin dispatch)
    const int t = b >> 3;
    if      (t < 489)  fillSegS(s0, d0, 1000000, cursor + DG_WRITES,  csr, t,        s * 25000, 25000);
    else if (t < 978)  fillSegS(s1, d1, 1000000, cursor + DG_RWRITES, csr, t - 489,  s * 12500, 12500);
    else if (t < 1467) fillSegS(s2, d2, 1000000, cursor + DG_CITES,   csr, t - 978,  s * 25000, 25000);
    else if (t < 1858) fillSegS(s3, d3,  800000, cursor + DG_HTOPIC,  csr, t - 1467, s * 6250,  6250);
    else if (t < 2249) fillSegS(s4, d4,  800000, cursor + DG_RHTOPIC, csr, t - 1858, s * 25000, 25000);
    else if (t < 2347) fillSegS(s5, d5,  200000, cursor + DG_AFFIL,   csr, t - 2249, s * 1000,  1000);
    else               fillSegS(s6, d6,  200000, cursor + DG_RAFFIL,  csr, t - 2347, s * 12500, 12500);
}

// ================= W prep: 8 matrices f32[128][64] -> bf16 Wt[64][128] ========
__global__ __launch_bounds__(256) void prep_wt(const float* __restrict__ W7,
                                               const float* __restrict__ slw,
                                               short* __restrict__ Wt) {
    const int mat = blockIdx.x;
    const float* Ws = (mat < 7) ? (W7 + (size_t)mat * IN_F * OUT_F) : slw;
    short* Wo = Wt + (size_t)mat * IN_F * OUT_F;
    for (int i = threadIdx.x; i < IN_F * OUT_F; i += 256) {
        int n = i >> 7;
        int k = i & 127;
        Wo[i] = f2bf(Ws[k * OUT_F + n]);
    }
}

// ================= merged MFMA projection =====================================
template <int R>
__device__ __forceinline__ void projBody(
    int blk, const float* __restrict__ X,
    const short* __restrict__ wt0, const short* __restrict__ wt1,
    const short* __restrict__ wt2, const short* __restrict__ wtS,
    const float* __restrict__ bias,
    bf16* __restrict__ Y0, bf16* __restrict__ Y1, bf16* __restrict__ Y2,
    float* __restrict__ OutSelf) {
    const int tid = threadIdx.x;
    const int wave = tid >> 6;
    const int lane = tid & 63;
    const int m = lane & 15;
    const int quad = lane >> 4;
    const int rowBase = blk * 16;
    const int ncol = wave * 16 + m;

    short8 af[4];
    const float* xrow = X + (size_t)(rowBase + m) * IN_F + quad * 8;
    #pragma unroll
    for (int kb = 0; kb < 4; kb++) {
        float4 x0 = *(const float4*)(xrow + kb * 32);
        float4 x1 = *(const float4*)(xrow + kb * 32 + 4);
        short8 a;
        a[0] = f2bf(x0.x); a[1] = f2bf(x0.y); a[2] = f2bf(x0.z); a[3] = f2bf(x0.w);
        a[4] = f2bf(x1.x); a[5] = f2bf(x1.y); a[6] = f2bf(x1.z); a[7] = f2bf(x1.w);
        af[kb] = a;
    }

    const short* wts[3] = {wt0, wt1, wt2};
    bf16* Ys[3] = {Y0, Y1, Y2};

    #pragma unroll
    for (int r = 0; r < R; r++) {
        const short* wrow = wts[r] + (size_t)ncol * IN_F + quad * 8;
        f32x4 acc = {0.f, 0.f, 0.f, 0.f};
        #pragma unroll
        for (int kb = 0; kb < 4; kb++) {
            short8 bfr = *(const short8*)(wrow + kb * 32);
            acc = __builtin_amdgcn_mfma_f32_16x16x32_bf16(af[kb], bfr, acc, 0, 0, 0);
        }
        bf16* Yr = Ys[r];
        #pragma unroll
        for (int reg = 0; reg < 4; reg++) {
            int row = rowBase + quad * 4 + reg;
            Yr[(size_t)row * OUT_F + ncol] = __float2bfloat16(acc[reg]);
        }
    }

    {
        const short* wrow = wtS + (size_t)ncol * IN_F + quad * 8;
        f32x4 acc = {0.f, 0.f, 0.f, 0.f};
        #pragma unroll
        for (int kb = 0; kb < 4; kb++) {
            short8 bfr = *(const short8*)(wrow + kb * 32);
            acc = __builtin_amdgcn_mfma_f32_16x16x32_bf16(af[kb], bfr, acc, 0, 0, 0);
        }
        const float b = bias[ncol];
        #pragma unroll
        for (int reg = 0; reg < 4; reg++) {
            int row = rowBase + quad * 4 + reg;
            OutSelf[(size_t)row * OUT_F + ncol] = acc[reg] + b;
        }
    }
}

// block ranges: paper 12500, author 6250, field 3125, inst 500 -> 22375 total
__global__ __launch_bounds__(256) void proj_all(
    const float* __restrict__ x_author, const float* __restrict__ x_field,
    const float* __restrict__ x_inst,   const float* __restrict__ x_paper,
    const short* __restrict__ wt, const float* __restrict__ bias,
    bf16* __restrict__ y, float* __restrict__ out) {
    int b = blockIdx.x;
    if (b < 12500) {
        projBody<3>(b, x_paper, wt + 1 * 8192, wt + 2 * 8192, wt + 3 * 8192, wt + 7 * 8192,
                    bias, y + YR_RWRITES * OUT_F, y + YR_CITES * OUT_F, y + YR_HTOPIC * OUT_F,
                    out + OUT_PAPER);
    } else if (b < 18750) {
        projBody<2>(b - 12500, x_author, wt + 0 * 8192, wt + 5 * 8192, nullptr, wt + 7 * 8192,
                    bias, y + YR_WRITES * OUT_F, y + YR_AFFIL * OUT_F, nullptr,
                    out + OUT_AUTHOR);
    } else if (b < 21875) {
        projBody<1>(b - 18750, x_field, wt + 4 * 8192, nullptr, nullptr, wt + 7 * 8192,
                    bias, y + YR_RHTOPIC * OUT_F, nullptr, nullptr,
                    out + OUT_FIELD);
    } else {
        projBody<1>(b - 21875, x_inst, wt + 6 * 8192, nullptr, nullptr, wt + 7 * 8192,
                    bias, y + YR_RAFFIL * OUT_F, nullptr, nullptr,
                    out + OUT_INST);
    }
}

// ================= merged gather: 8 lanes/edge, uint4 loads ===================
template <int NR>
__device__ __forceinline__ void gatherNode(
    int n, int lane, const int* __restrict__ csr,
    const int* __restrict__ off0, const uint4* __restrict__ y0,
    const int* __restrict__ off1, const uint4* __restrict__ y1,
    const int* __restrict__ off2, const uint4* __restrict__ y2,
    float* __restrict__ out) {
    const int g = lane >> 3;
    const int f = lane & 7;
    const int* offs[3] = {off0, off1, off2};
    const uint4* ys[3] = {y0, y1, y2};
    float acc[8] = {0.f, 0.f, 0.f, 0.f, 0.f, 0.f, 0.f, 0.f};
    #pragma unroll
    for (int r = 0; r < NR; r++) {
        const int s = offs[r][n];
        const int e = offs[r][n + 1];
        const uint4* __restrict__ yr = ys[r];
        float racc[8] = {0.f, 0.f, 0.f, 0.f, 0.f, 0.f, 0.f, 0.f};
        for (int j = s; j < e; j += 16) {
            int i0 = j + g;
            int i1 = j + 8 + g;
            int c0 = csr[min(i0, e - 1)];
            int c1 = csr[min(i1, e - 1)];
            uint4 u0 = yr[(size_t)c0 * 8 + f];
            uint4 u1 = yr[(size_t)c1 * 8 + f];
            float m0 = (i0 < e) ? 1.f : 0.f;
            float m1 = (i1 < e) ? 1.f : 0.f;
            racc[0] += m0 * bflo(u0.x); racc[1] += m0 * bfhi(u0.x);
            racc[2] += m0 * bflo(u0.y); racc[3] += m0 * bfhi(u0.y);
            racc[4] += m0 * bflo(u0.z); racc[5] += m0 * bfhi(u0.z);
            racc[6] += m0 * bflo(u0.w); racc[7] += m0 * bfhi(u0.w);
            racc[0] += m1 * bflo(u1.x); racc[1] += m1 * bfhi(u1.x);
            racc[2] += m1 * bflo(u1.y); racc[3] += m1 * bfhi(u1.y);
            racc[4] += m1 * bflo(u1.z); racc[5] += m1 * bfhi(u1.z);
            racc[6] += m1 * bflo(u1.w); racc[7] += m1 * bfhi(u1.w);
        }
        int dg = e - s;
        float inv = 1.0f / (float)(dg > 1 ? dg : 1);
        #pragma unroll
        for (int k = 0; k < 8; k++) acc[k] += racc[k] * inv;
    }
    #pragma unroll
    for (int d = 8; d <= 32; d <<= 1) {
        #pragma unroll
        for (int k = 0; k < 8; k++) acc[k] += __shfl_xor(acc[k], d, 64);
    }
    if (lane < 8) {
        float* orow = out + (size_t)n * OUT_F + f * 8;
        float4 c0 = *(float4*)orow;
        float4 c1 = *(float4*)(orow + 4);
        c0.x = fmaxf(c0.x + acc[0], 0.f); c0.y = fmaxf(c0.y + acc[1], 0.f);
        c0.z = fmaxf(c0.z + acc[2], 0.f); c0.w = fmaxf(c0.w + acc[3], 0.f);
        c1.x = fmaxf(c1.x + acc[4], 0.f); c1.y = fmaxf(c1.y + acc[5], 0.f);
        c1.z = fmaxf(c1.z + acc[6], 0.f); c1.w = fmaxf(c1.w + acc[7], 0.f);
        *(float4*)orow = c0;
        *(float4*)(orow + 4) = c1;
    }
}

// block ranges (4 nodes/block): paper 50000, author 25000, field 12500, inst 2000
__global__ __launch_bounds__(256) void gather_all(
    const int* __restrict__ csr, const int* __restrict__ off,
    const bf16* __restrict__ y, float* __restrict__ out) {
    const int b = blockIdx.x;
    const int tid = threadIdx.x;
    const int lane = tid & 63;
    const int wv = tid >> 6;
    if (b < 50000) {
        gatherNode<3>(b * 4 + wv, lane, csr,
                      off + DG_WRITES,  (const uint4*)(y + YR_WRITES * OUT_F),
                      off + DG_CITES,   (const uint4*)(y + YR_CITES * OUT_F),
                      off + DG_RHTOPIC, (const uint4*)(y + YR_RHTOPIC * OUT_F),
                      out + OUT_PAPER);
    } else if (b < 75000) {
        gatherNode<2>((b - 50000) * 4 + wv, lane, csr,
                      off + DG_RWRITES, (const uint4*)(y + YR_RWRITES * OUT_F),
                      off + DG_RAFFIL,  (const uint4*)(y + YR_RAFFIL * OUT_F),
                      nullptr, nullptr,
                      out + OUT_AUTHOR);
    } else if (b < 87500) {
        gatherNode<1>((b - 75000) * 4 + wv, lane, csr,
                      off + DG_HTOPIC, (const uint4*)(y + YR_HTOPIC * OUT_F),
                      nullptr, nullptr, nullptr, nullptr,
                      out + OUT_FIELD);
    } else {
        gatherNode<1>((b - 87500) * 4 + wv, lane, csr,
                      off + DG_AFFIL, (const uint4*)(y + YR_AFFIL * OUT_F),
                      nullptr, nullptr, nullptr, nullptr,
                      out + OUT_INST);
    }
}

extern "C" void kernel_launch(void* const* d_in, const int* in_sizes, int n_in,
                              void* d_out, int out_size, void* d_ws, size_t ws_size,
                              hipStream_t stream) {
    (void)in_sizes; (void)n_in; (void)ws_size; (void)out_size;

    const float* x_author = (const float*)d_in[0];
    const float* x_field  = (const float*)d_in[1];
    const float* x_inst   = (const float*)d_in[2];
    const float* x_paper  = (const float*)d_in[3];
    const float* weight   = (const float*)d_in[4];
    const float* slw      = (const float*)d_in[5];
    const float* bias     = (const float*)d_in[6];
    float* out = (float*)d_out;

    // ---- workspace layout ----
    char* w = (char*)d_ws;
    auto alignup = [](size_t v) { return (v + 127) & ~(size_t)127; };
    bf16* y  = (bf16*)w;              size_t o1 = alignup((size_t)N_NODES * OUT_F * sizeof(bf16));
    int* deg = (int*)(w + o1);        size_t o2 = o1 + alignup((size_t)N_NODES * sizeof(int));
    int* off = (int*)(w + o2);        size_t o3 = o2 + alignup(((size_t)N_NODES + 4) * sizeof(int));
    int* cursor = (int*)(w + o3);     size_t o4 = o3 + alignup((size_t)N_NODES * sizeof(int));
    int* csr = (int*)(w + o4);        size_t o5 = o4 + alignup((size_t)E_TOTAL * sizeof(int));
    int* bsums = (int*)(w + o5);      size_t o6 = o5 + alignup(2048 * sizeof(int));
    short* wt = (short*)(w + o6);

    const int* ws_p[7] = {(const int*)d_in[7],  (const int*)d_in[9],  (const int*)d_in[11],
                          (const int*)d_in[13], (const int*)d_in[15], (const int*)d_in[17],
                          (const int*)d_in[19]};
    const int* wd_p[7] = {(const int*)d_in[8],  (const int*)d_in[10], (const int*)d_in[12],
                          (const int*)d_in[14], (const int*)d_in[16], (const int*)d_in[18],
                          (const int*)d_in[20]};

    const int NBLK = (N_NODES + 1023) / 1024;   // 838
    const int SLICE_BLKS = 8 * 2445;            // 19560

    // 1) W transpose+cast (no deps)
    prep_wt<<<8, 256, 0, stream>>>(weight, slw, wt);

    // 2) degrees (XCD-sliced)
    hipMemsetAsync(deg, 0, (size_t)N_NODES * sizeof(int), stream);
    deg_all<<<SLICE_BLKS, 256, 0, stream>>>(wd_p[0], wd_p[1], wd_p[2], wd_p[3],
                                            wd_p[4], wd_p[5], wd_p[6], deg);

    // 3) scan -> off, cursor
    scan1<<<NBLK, 256, 0, stream>>>(deg, off, bsums, N_NODES);
    scan2<<<1, 1024, 0, stream>>>(bsums, NBLK);
    scan3<<<NBLK, 256, 0, stream>>>(off, cursor, bsums, N_NODES, E_TOTAL);

    // 4) CSR fill (XCD-sliced)
    fill_all<<<SLICE_BLKS, 256, 0, stream>>>(ws_p[0], wd_p[0], ws_p[1], wd_p[1],
                                             ws_p[2], wd_p[2], ws_p[3], wd_p[3],
                                             ws_p[4], wd_p[4], ws_p[5], wd_p[5],
                                             ws_p[6], wd_p[6], cursor, csr);

    // 5) fused MFMA projections + self-loop init
    proj_all<<<22375, 256, 0, stream>>>(x_author, x_field, x_inst, x_paper,
                                        wt, bias, y, out);

    // 6) fused gather + norm + selfloop-add + relu
    gather_all<<<89500, 256, 0, stream>>>(csr, off, y, out);
}

// Round 4
// 1063.234 us; speedup vs baseline: 1.2204x; 1.0422x over previous
//
#include <hip/hip_runtime.h>
#include <hip/hip_bf16.h>

#define IN_F 128
#define OUT_F 64

typedef __hip_bfloat16 bf16;
typedef __attribute__((ext_vector_type(8))) short short8;
typedef __attribute__((ext_vector_type(4))) float f32x4;

// ---------------- problem constants (all compile-time) ----------------
#define N_AUTHOR 100000
#define N_PAPER  200000
#define N_FIELD  50000
#define N_INST   8000
#define N_NODES  858000
#define E_TOTAL  5000000

// output segment bases (floats)
#define OUT_AUTHOR 0L
#define OUT_FIELD  (6400000L)     // N_AUTHOR*64
#define OUT_INST   (9600000L)     // + N_FIELD*64
#define OUT_PAPER  (10112000L)    // + N_INST*64

// deg/off segment bases (per destination of each relation)
#define DG_WRITES   0
#define DG_RWRITES  200000
#define DG_CITES    300000
#define DG_HTOPIC   500000
#define DG_RHTOPIC  550000
#define DG_AFFIL    750000
#define DG_RAFFIL   758000

// y-table row bases (per relation)
#define YR_WRITES   0L
#define YR_RWRITES  100000L
#define YR_CITES    300000L
#define YR_HTOPIC   500000L
#define YR_RHTOPIC  700000L
#define YR_AFFIL    750000L
#define YR_RAFFIL   850000L

__device__ inline short f2bf(float f) {
    __hip_bfloat16 h = __float2bfloat16(f);
    return __builtin_bit_cast(short, h);
}
__device__ inline float bflo(unsigned u) {
    unsigned v = u << 16;
    return __builtin_bit_cast(float, v);
}
__device__ inline float bfhi(unsigned u) {
    unsigned v = u & 0xFFFF0000u;
    return __builtin_bit_cast(float, v);
}

// ============ XCD-sliced degree count ============
__device__ __forceinline__ void degSegS(const int* __restrict__ dst, int E,
                                        int* __restrict__ deg, int chunk,
                                        int lo, int wid) {
    const int base = chunk * 2048 + (int)threadIdx.x * 4;
    #pragma unroll
    for (int it = 0; it < 2; it++) {
        int i = base + it * 1024;
        if (i + 3 < E) {
            int4 d = *(const int4*)(dst + i);
            if ((unsigned)(d.x - lo) < (unsigned)wid) atomicAdd(&deg[d.x], 1);
            if ((unsigned)(d.y - lo) < (unsigned)wid) atomicAdd(&deg[d.y], 1);
            if ((unsigned)(d.z - lo) < (unsigned)wid) atomicAdd(&deg[d.z], 1);
            if ((unsigned)(d.w - lo) < (unsigned)wid) atomicAdd(&deg[d.w], 1);
        } else {
            for (int k = 0; k < 4; k++) {
                int ii = i + k;
                if (ii < E) {
                    int dd = dst[ii];
                    if ((unsigned)(dd - lo) < (unsigned)wid) atomicAdd(&deg[dd], 1);
                }
            }
        }
    }
}

// chunk counts: 1M->489, 800k->391, 200k->98 ; per-slice total 2445; grid 19560
__global__ __launch_bounds__(256) void deg_all(
    const int* d0, const int* d1, const int* d2, const int* d3,
    const int* d4, const int* d5, const int* d6, int* __restrict__ deg) {
    const int b = blockIdx.x;
    const int s = b & 7;         // slice -> XCD (round-robin dispatch)
    const int t = b >> 3;
    if      (t < 489)  degSegS(d0, 1000000, deg + DG_WRITES,  t,        s * 25000, 25000);
    else if (t < 978)  degSegS(d1, 1000000, deg + DG_RWRITES, t - 489,  s * 12500, 12500);
    else if (t < 1467) degSegS(d2, 1000000, deg + DG_CITES,   t - 978,  s * 25000, 25000);
    else if (t < 1858) degSegS(d3,  800000, deg + DG_HTOPIC,  t - 1467, s * 6250,  6250);
    else if (t < 2249) degSegS(d4,  800000, deg + DG_RHTOPIC, t - 1858, s * 25000, 25000);
    else if (t < 2347) degSegS(d5,  200000, deg + DG_AFFIL,   t - 2249, s * 1000,  1000);
    else               degSegS(d6,  200000, deg + DG_RAFFIL,  t - 2347, s * 12500, 12500);
}

// ================= 3-phase exclusive scan =================
__global__ __launch_bounds__(256) void scan1(const int* __restrict__ deg,
                                             int* __restrict__ off,
                                             int* __restrict__ bsums, int n) {
    __shared__ int ts[256];
    const int tid = threadIdx.x;
    const int base = blockIdx.x * 1024 + tid * 4;
    int4 v = {0, 0, 0, 0};
    if (base < n) v = *(const int4*)(deg + base);
    int sum = v.x + v.y + v.z + v.w;
    ts[tid] = sum;
    __syncthreads();
    for (int o = 1; o < 256; o <<= 1) {
        int t = (tid >= o) ? ts[tid - o] : 0;
        __syncthreads();
        ts[tid] += t;
        __syncthreads();
    }
    int pre = ts[tid] - sum;
    if (base < n) {
        int4 e;
        e.x = pre;
        e.y = pre + v.x;
        e.z = pre + v.x + v.y;
        e.w = pre + v.x + v.y + v.z;
        *(int4*)(off + base) = e;
    }
    if (tid == 255) bsums[blockIdx.x] = ts[255];
}

__global__ __launch_bounds__(1024) void scan2(int* __restrict__ bsums, int nb) {
    __shared__ int ts[1024];
    const int tid = threadIdx.x;
    int v = (tid < nb) ? bsums[tid] : 0;
    ts[tid] = v;
    __syncthreads();
    for (int o = 1; o < 1024; o <<= 1) {
        int t = (tid >= o) ? ts[tid - o] : 0;
        __syncthreads();
        ts[tid] += t;
        __syncthreads();
    }
    if (tid < nb) bsums[tid] = ts[tid] - v;
}

__global__ __launch_bounds__(256) void scan3(int* __restrict__ off,
                                             int* __restrict__ cursor,
                                             const int* __restrict__ bsums,
                                             int n, int e_total) {
    const int tid = threadIdx.x;
    const int base = blockIdx.x * 1024 + tid * 4;
    const int bp = bsums[blockIdx.x];
    if (base < n) {
        int4 v = *(const int4*)(off + base);
        v.x += bp; v.y += bp; v.z += bp; v.w += bp;
        *(int4*)(off + base) = v;
        *(int4*)(cursor + base) = v;
    }
    if (blockIdx.x == 0 && tid == 0) off[n] = e_total;
}

// ============ XCD-sliced CSR fill ============
__device__ __forceinline__ void fillSegS(const int* __restrict__ src,
                                         const int* __restrict__ dst, int E,
                                         int* __restrict__ cursor,
                                         int* __restrict__ csr, int chunk,
                                         int lo, int wid) {
    const int base = chunk * 2048 + (int)threadIdx.x * 4;
    #pragma unroll
    for (int it = 0; it < 2; it++) {
        int i = base + it * 1024;
        if (i + 3 < E) {
            int4 d = *(const int4*)(dst + i);
            int4 sv = *(const int4*)(src + i);
            if ((unsigned)(d.x - lo) < (unsigned)wid) { int p = atomicAdd(&cursor[d.x], 1); csr[p] = sv.x; }
            if ((unsigned)(d.y - lo) < (unsigned)wid) { int p = atomicAdd(&cursor[d.y], 1); csr[p] = sv.y; }
            if ((unsigned)(d.z - lo) < (unsigned)wid) { int p = atomicAdd(&cursor[d.z], 1); csr[p] = sv.z; }
            if ((unsigned)(d.w - lo) < (unsigned)wid) { int p = atomicAdd(&cursor[d.w], 1); csr[p] = sv.w; }
        } else {
            for (int k = 0; k < 4; k++) {
                int ii = i + k;
                if (ii < E) {
                    int dd = dst[ii];
                    if ((unsigned)(dd - lo) < (unsigned)wid) {
                        int p = atomicAdd(&cursor[dd], 1);
                        csr[p] = src[ii];
                    }
                }
            }
        }
    }
}

__global__ __launch_bounds__(256) void fill_all(
    const int* s0, const int* d0, const int* s1, const int* d1,
    const int* s2, const int* d2, const int* s3, const int* d3,
    const int* s4, const int* d4, const int* s5, const int* d5,
    const int* s6, const int* d6,
    int* __restrict__ cursor, int* __restrict__ csr) {
    const int b = blockIdx.x;
    const int s = b & 7;         // slice -> XCD (round-robin dispatch)
    const int t = b >> 3;
    if      (t < 489)  fillSegS(s0, d0, 1000000, cursor + DG_WRITES,  csr, t,        s * 25000, 25000);
    else if (t < 978)  fillSegS(s1, d1, 1000000, cursor + DG_RWRITES, csr, t - 489,  s * 12500, 12500);
    else if (t < 1467) fillSegS(s2, d2, 1000000, cursor + DG_CITES,   csr, t - 978,  s * 25000, 25000);
    else if (t < 1858) fillSegS(s3, d3,  800000, cursor + DG_HTOPIC,  csr, t - 1467, s * 6250,  6250);
    else if (t < 2249) fillSegS(s4, d4,  800000, cursor + DG_RHTOPIC, csr, t - 1858, s * 25000, 25000);
    else if (t < 2347) fillSegS(s5, d5,  200000, cursor + DG_AFFIL,   csr, t - 2249, s * 1000,  1000);
    else               fillSegS(s6, d6,  200000, cursor + DG_RAFFIL,  csr, t - 2347, s * 12500, 12500);
}

// ================= W prep: 8 matrices f32[128][64] -> bf16 Wt[64][128] ========
__global__ __launch_bounds__(256) void prep_wt(const float* __restrict__ W7,
                                               const float* __restrict__ slw,
                                               short* __restrict__ Wt) {
    const int mat = blockIdx.x;
    const float* Ws = (mat < 7) ? (W7 + (size_t)mat * IN_F * OUT_F) : slw;
    short* Wo = Wt + (size_t)mat * IN_F * OUT_F;
    for (int i = threadIdx.x; i < IN_F * OUT_F; i += 256) {
        int n = i >> 7;
        int k = i & 127;
        Wo[i] = f2bf(Ws[k * OUT_F + n]);
    }
}

// ================= merged MFMA projection (64 rows/block, wave-owns-rows) =====
// Each wave handles its own 16 rows and computes ALL 64 output cols via 4
// col-blocks: X load + f32->bf16 cvt happen once per row (was 4x redundant
// across the block's waves).
template <int R>
__device__ __forceinline__ void projBody(
    int blk, int nrows, const float* __restrict__ X,
    const short* __restrict__ wt0, const short* __restrict__ wt1,
    const short* __restrict__ wt2, const short* __restrict__ wtS,
    const float* __restrict__ bias,
    bf16* __restrict__ Y0, bf16* __restrict__ Y1, bf16* __restrict__ Y2,
    float* __restrict__ OutSelf) {
    const int tid = threadIdx.x;
    const int wave = tid >> 6;
    const int lane = tid & 63;
    const int m = lane & 15;
    const int quad = lane >> 4;
    const int rowBase = blk * 64 + wave * 16;
    if (rowBase >= nrows) return;                 // wave-uniform early out
    const bool full = (rowBase + 16 <= nrows);    // wave-uniform fast path

    int arow = rowBase + m;
    if (arow > nrows - 1) arow = nrows - 1;       // clamp load row

    short8 af[4];
    const float* xrow = X + (size_t)arow * IN_F + quad * 8;
    #pragma unroll
    for (int kb = 0; kb < 4; kb++) {
        float4 x0 = *(const float4*)(xrow + kb * 32);
        float4 x1 = *(const float4*)(xrow + kb * 32 + 4);
        short8 a;
        a[0] = f2bf(x0.x); a[1] = f2bf(x0.y); a[2] = f2bf(x0.z); a[3] = f2bf(x0.w);
        a[4] = f2bf(x1.x); a[5] = f2bf(x1.y); a[6] = f2bf(x1.z); a[7] = f2bf(x1.w);
        af[kb] = a;
    }

    const short* wts[3] = {wt0, wt1, wt2};
    bf16* Ys[3] = {Y0, Y1, Y2};

    #pragma unroll
    for (int r = 0; r < R; r++) {
        bf16* Yr = Ys[r];
        #pragma unroll
        for (int cb = 0; cb < 4; cb++) {
            const int ncol = cb * 16 + m;
            const short* wrow = wts[r] + (size_t)ncol * IN_F + quad * 8;
            f32x4 acc = {0.f, 0.f, 0.f, 0.f};
            #pragma unroll
            for (int kb = 0; kb < 4; kb++) {
                short8 bfr = *(const short8*)(wrow + kb * 32);
                acc = __builtin_amdgcn_mfma_f32_16x16x32_bf16(af[kb], bfr, acc, 0, 0, 0);
            }
            if (full) {
                #pragma unroll
                for (int reg = 0; reg < 4; reg++) {
                    int row = rowBase + quad * 4 + reg;
                    Yr[(size_t)row * OUT_F + ncol] = __float2bfloat16(acc[reg]);
                }
            } else {
                #pragma unroll
                for (int reg = 0; reg < 4; reg++) {
                    int row = rowBase + quad * 4 + reg;
                    if (row < nrows)
                        Yr[(size_t)row * OUT_F + ncol] = __float2bfloat16(acc[reg]);
                }
            }
        }
    }

    // self-loop + bias -> f32 out
    #pragma unroll
    for (int cb = 0; cb < 4; cb++) {
        const int ncol = cb * 16 + m;
        const short* wrow = wtS + (size_t)ncol * IN_F + quad * 8;
        f32x4 acc = {0.f, 0.f, 0.f, 0.f};
        #pragma unroll
        for (int kb = 0; kb < 4; kb++) {
            short8 bfr = *(const short8*)(wrow + kb * 32);
            acc = __builtin_amdgcn_mfma_f32_16x16x32_bf16(af[kb], bfr, acc, 0, 0, 0);
        }
        const float b = bias[ncol];
        if (full) {
            #pragma unroll
            for (int reg = 0; reg < 4; reg++) {
                int row = rowBase + quad * 4 + reg;
                OutSelf[(size_t)row * OUT_F + ncol] = acc[reg] + b;
            }
        } else {
            #pragma unroll
            for (int reg = 0; reg < 4; reg++) {
                int row = rowBase + quad * 4 + reg;
                if (row < nrows)
                    OutSelf[(size_t)row * OUT_F + ncol] = acc[reg] + b;
            }
        }
    }
}

// block ranges (64 rows/blk): paper 3125, author 1563, field 782, inst 125 -> 5595
__global__ __launch_bounds__(256) void proj_all(
    const float* __restrict__ x_author, const float* __restrict__ x_field,
    const float* __restrict__ x_inst,   const float* __restrict__ x_paper,
    const short* __restrict__ wt, const float* __restrict__ bias,
    bf16* __restrict__ y, float* __restrict__ out) {
    int b = blockIdx.x;
    if (b < 3125) {
        projBody<3>(b, N_PAPER, x_paper, wt + 1 * 8192, wt + 2 * 8192, wt + 3 * 8192, wt + 7 * 8192,
                    bias, y + YR_RWRITES * OUT_F, y + YR_CITES * OUT_F, y + YR_HTOPIC * OUT_F,
                    out + OUT_PAPER);
    } else if (b < 4688) {
        projBody<2>(b - 3125, N_AUTHOR, x_author, wt + 0 * 8192, wt + 5 * 8192, nullptr, wt + 7 * 8192,
                    bias, y + YR_WRITES * OUT_F, y + YR_AFFIL * OUT_F, nullptr,
                    out + OUT_AUTHOR);
    } else if (b < 5470) {
        projBody<1>(b - 4688, N_FIELD, x_field, wt + 4 * 8192, nullptr, nullptr, wt + 7 * 8192,
                    bias, y + YR_RHTOPIC * OUT_F, nullptr, nullptr,
                    out + OUT_FIELD);
    } else {
        projBody<1>(b - 5470, N_INST, x_inst, wt + 6 * 8192, nullptr, nullptr, wt + 7 * 8192,
                    bias, y + YR_RAFFIL * OUT_F, nullptr, nullptr,
                    out + OUT_INST);
    }
}

// ================= merged gather: 8 lanes/edge, 8-slot iterations =============
// avg segment degree ~5.8 -> 8 edge-slots per iteration (one uint4/lane) halves
// the mandatory per-segment work vs 16-slot. 32-bit byte offsets off uniform
// bases let the compiler emit s-base+voffset loads (no 64-bit VALU addr chains).
template <int NR>
__device__ __forceinline__ void gatherNode(
    int n, int lane, const char* __restrict__ csrb,
    const int* __restrict__ off0, const char* __restrict__ y0,
    const int* __restrict__ off1, const char* __restrict__ y1,
    const int* __restrict__ off2, const char* __restrict__ y2,
    float* __restrict__ out) {
    const int g = lane >> 3;
    const int f = lane & 7;
    const unsigned foff = (unsigned)f << 4;
    const int* offs[3] = {off0, off1, off2};
    const char* ys[3] = {y0, y1, y2};
    float acc[8] = {0.f, 0.f, 0.f, 0.f, 0.f, 0.f, 0.f, 0.f};
    #pragma unroll
    for (int r = 0; r < NR; r++) {
        const int s = offs[r][n];
        const int e = offs[r][n + 1];
        const char* __restrict__ yb = ys[r];
        float racc[8] = {0.f, 0.f, 0.f, 0.f, 0.f, 0.f, 0.f, 0.f};
        for (int j = s; j < e; j += 8) {
            int i = j + g;
            int ic = min(i, e - 1);
            int c = *(const int*)(csrb + ((unsigned)ic << 2));
            uint4 u = *(const uint4*)(yb + ((unsigned)c << 7) + foff);
            float mk = (i < e) ? 1.f : 0.f;
            racc[0] += mk * bflo(u.x); racc[1] += mk * bfhi(u.x);
            racc[2] += mk * bflo(u.y); racc[3] += mk * bfhi(u.y);
            racc[4] += mk * bflo(u.z); racc[5] += mk * bfhi(u.z);
            racc[6] += mk * bflo(u.w); racc[7] += mk * bfhi(u.w);
        }
        float dg = (float)(e - s);
        float inv = __builtin_amdgcn_rcpf(dg > 1.f ? dg : 1.f);
        #pragma unroll
        for (int k = 0; k < 8; k++) acc[k] += racc[k] * inv;
    }
    #pragma unroll
    for (int d = 8; d <= 32; d <<= 1) {
        #pragma unroll
        for (int k = 0; k < 8; k++) acc[k] += __shfl_xor(acc[k], d, 64);
    }
    if (lane < 8) {
        float* orow = out + (size_t)n * OUT_F + f * 8;
        float4 c0 = *(float4*)orow;
        float4 c1 = *(float4*)(orow + 4);
        c0.x = fmaxf(c0.x + acc[0], 0.f); c0.y = fmaxf(c0.y + acc[1], 0.f);
        c0.z = fmaxf(c0.z + acc[2], 0.f); c0.w = fmaxf(c0.w + acc[3], 0.f);
        c1.x = fmaxf(c1.x + acc[4], 0.f); c1.y = fmaxf(c1.y + acc[5], 0.f);
        c1.z = fmaxf(c1.z + acc[6], 0.f); c1.w = fmaxf(c1.w + acc[7], 0.f);
        *(float4*)orow = c0;
        *(float4*)(orow + 4) = c1;
    }
}

// block ranges (4 nodes/block): paper 50000, author 25000, field 12500, inst 2000
__global__ __launch_bounds__(256) void gather_all(
    const int* __restrict__ csr, const int* __restrict__ off,
    const bf16* __restrict__ y, float* __restrict__ out) {
    const int b = blockIdx.x;
    const int tid = threadIdx.x;
    const int lane = tid & 63;
    const int wv = tid >> 6;
    const char* csrb = (const char*)csr;
    if (b < 50000) {
        gatherNode<3>(b * 4 + wv, lane, csrb,
                      off + DG_WRITES,  (const char*)(y + YR_WRITES * OUT_F),
                      off + DG_CITES,   (const char*)(y + YR_CITES * OUT_F),
                      off + DG_RHTOPIC, (const char*)(y + YR_RHTOPIC * OUT_F),
                      out + OUT_PAPER);
    } else if (b < 75000) {
        gatherNode<2>((b - 50000) * 4 + wv, lane, csrb,
                      off + DG_RWRITES, (const char*)(y + YR_RWRITES * OUT_F),
                      off + DG_RAFFIL,  (const char*)(y + YR_RAFFIL * OUT_F),
                      nullptr, nullptr,
                      out + OUT_AUTHOR);
    } else if (b < 87500) {
        gatherNode<1>((b - 75000) * 4 + wv, lane, csrb,
                      off + DG_HTOPIC, (const char*)(y + YR_HTOPIC * OUT_F),
                      nullptr, nullptr, nullptr, nullptr,
                      out + OUT_FIELD);
    } else {
        gatherNode<1>((b - 87500) * 4 + wv, lane, csrb,
                      off + DG_AFFIL, (const char*)(y + YR_AFFIL * OUT_F),
                      nullptr, nullptr, nullptr, nullptr,
                      out + OUT_INST);
    }
}

extern "C" void kernel_launch(void* const* d_in, const int* in_sizes, int n_in,
                              void* d_out, int out_size, void* d_ws, size_t ws_size,
                              hipStream_t stream) {
    (void)in_sizes; (void)n_in; (void)ws_size; (void)out_size;

    const float* x_author = (const float*)d_in[0];
    const float* x_field  = (const float*)d_in[1];
    const float* x_inst   = (const float*)d_in[2];
    const float* x_paper  = (const float*)d_in[3];
    const float* weight   = (const float*)d_in[4];
    const float* slw      = (const float*)d_in[5];
    const float* bias     = (const float*)d_in[6];
    float* out = (float*)d_out;

    // ---- workspace layout ----
    char* w = (char*)d_ws;
    auto alignup = [](size_t v) { return (v + 127) & ~(size_t)127; };
    bf16* y  = (bf16*)w;              size_t o1 = alignup((size_t)N_NODES * OUT_F * sizeof(bf16));
    int* deg = (int*)(w + o1);        size_t o2 = o1 + alignup((size_t)N_NODES * sizeof(int));
    int* off = (int*)(w + o2);        size_t o3 = o2 + alignup(((size_t)N_NODES + 4) * sizeof(int));
    int* cursor = (int*)(w + o3);     size_t o4 = o3 + alignup((size_t)N_NODES * sizeof(int));
    int* csr = (int*)(w + o4);        size_t o5 = o4 + alignup((size_t)E_TOTAL * sizeof(int));
    int* bsums = (int*)(w + o5);      size_t o6 = o5 + alignup(2048 * sizeof(int));
    short* wt = (short*)(w + o6);

    const int* ws_p[7] = {(const int*)d_in[7],  (const int*)d_in[9],  (const int*)d_in[11],
                          (const int*)d_in[13], (const int*)d_in[15], (const int*)d_in[17],
                          (const int*)d_in[19]};
    const int* wd_p[7] = {(const int*)d_in[8],  (const int*)d_in[10], (const int*)d_in[12],
                          (const int*)d_in[14], (const int*)d_in[16], (const int*)d_in[18],
                          (const int*)d_in[20]};

    const int NBLK = (N_NODES + 1023) / 1024;   // 838
    const int SLICE_BLKS = 8 * 2445;            // 19560

    // 1) W transpose+cast (no deps)
    prep_wt<<<8, 256, 0, stream>>>(weight, slw, wt);

    // 2) degrees (XCD-sliced)
    hipMemsetAsync(deg, 0, (size_t)N_NODES * sizeof(int), stream);
    deg_all<<<SLICE_BLKS, 256, 0, stream>>>(wd_p[0], wd_p[1], wd_p[2], wd_p[3],
                                            wd_p[4], wd_p[5], wd_p[6], deg);

    // 3) scan -> off, cursor
    scan1<<<NBLK, 256, 0, stream>>>(deg, off, bsums, N_NODES);
    scan2<<<1, 1024, 0, stream>>>(bsums, NBLK);
    scan3<<<NBLK, 256, 0, stream>>>(off, cursor, bsums, N_NODES, E_TOTAL);

    // 4) CSR fill (XCD-sliced)
    fill_all<<<SLICE_BLKS, 256, 0, stream>>>(ws_p[0], wd_p[0], ws_p[1], wd_p[1],
                                             ws_p[2], wd_p[2], ws_p[3], wd_p[3],
                                             ws_p[4], wd_p[4], ws_p[5], wd_p[5],
                                             ws_p[6], wd_p[6], cursor, csr);

    // 5) fused MFMA projections + self-loop init (64 rows/block)
    proj_all<<<5595, 256, 0, stream>>>(x_author, x_field, x_inst, x_paper,
                                       wt, bias, y, out);

    // 6) fused gather + norm + selfloop-add + relu
    gather_all<<<89500, 256, 0, stream>>>(csr, off, y, out);
}

// Round 5
// 1007.290 us; speedup vs baseline: 1.2882x; 1.0555x over previous
//
#include <hip/hip_runtime.h>
#include <hip/hip_bf16.h>

#define IN_F 128
#define OUT_F 64

typedef __hip_bfloat16 bf16;
typedef __attribute__((ext_vector_type(8))) short short8;
typedef __attribute__((ext_vector_type(4))) float f32x4;

// ---------------- problem constants (all compile-time) ----------------
#define N_AUTHOR 100000
#define N_PAPER  200000
#define N_FIELD  50000
#define N_INST   8000
#define N_NODES  858000
#define E_TOTAL  5000000

// output segment bases (floats)
#define OUT_AUTHOR 0L
#define OUT_FIELD  (6400000L)     // N_AUTHOR*64
#define OUT_INST   (9600000L)     // + N_FIELD*64
#define OUT_PAPER  (10112000L)    // + N_INST*64

// deg/off segment bases (per destination of each relation)
#define DG_WRITES   0
#define DG_RWRITES  200000
#define DG_CITES    300000
#define DG_HTOPIC   500000
#define DG_RHTOPIC  550000
#define DG_AFFIL    750000
#define DG_RAFFIL   758000

// y-table row bases (per relation)
#define YR_WRITES   0L
#define YR_RWRITES  100000L
#define YR_CITES    300000L
#define YR_HTOPIC   500000L
#define YR_RHTOPIC  700000L
#define YR_AFFIL    750000L
#define YR_RAFFIL   850000L

__device__ inline short f2bf(float f) {
    __hip_bfloat16 h = __float2bfloat16(f);
    return __builtin_bit_cast(short, h);
}
__device__ inline float bflo(unsigned u) {
    unsigned v = u << 16;
    return __builtin_bit_cast(float, v);
}
__device__ inline float bfhi(unsigned u) {
    unsigned v = u & 0xFFFF0000u;
    return __builtin_bit_cast(float, v);
}

// ============ XCD-sliced degree count ============
__device__ __forceinline__ void degSegS(const int* __restrict__ dst, int E,
                                        int* __restrict__ deg, int chunk,
                                        int lo, int wid) {
    const int base = chunk * 2048 + (int)threadIdx.x * 4;
    #pragma unroll
    for (int it = 0; it < 2; it++) {
        int i = base + it * 1024;
        if (i + 3 < E) {
            int4 d = *(const int4*)(dst + i);
            if ((unsigned)(d.x - lo) < (unsigned)wid) atomicAdd(&deg[d.x], 1);
            if ((unsigned)(d.y - lo) < (unsigned)wid) atomicAdd(&deg[d.y], 1);
            if ((unsigned)(d.z - lo) < (unsigned)wid) atomicAdd(&deg[d.z], 1);
            if ((unsigned)(d.w - lo) < (unsigned)wid) atomicAdd(&deg[d.w], 1);
        } else {
            for (int k = 0; k < 4; k++) {
                int ii = i + k;
                if (ii < E) {
                    int dd = dst[ii];
                    if ((unsigned)(dd - lo) < (unsigned)wid) atomicAdd(&deg[dd], 1);
                }
            }
        }
    }
}

// chunk counts: 1M->489, 800k->391, 200k->98 ; per-slice total 2445; grid 19560
__global__ __launch_bounds__(256) void deg_all(
    const int* d0, const int* d1, const int* d2, const int* d3,
    const int* d4, const int* d5, const int* d6, int* __restrict__ deg) {
    const int b = blockIdx.x;
    const int s = b & 7;         // slice -> XCD (round-robin dispatch)
    const int t = b >> 3;
    if      (t < 489)  degSegS(d0, 1000000, deg + DG_WRITES,  t,        s * 25000, 25000);
    else if (t < 978)  degSegS(d1, 1000000, deg + DG_RWRITES, t - 489,  s * 12500, 12500);
    else if (t < 1467) degSegS(d2, 1000000, deg + DG_CITES,   t - 978,  s * 25000, 25000);
    else if (t < 1858) degSegS(d3,  800000, deg + DG_HTOPIC,  t - 1467, s * 6250,  6250);
    else if (t < 2249) degSegS(d4,  800000, deg + DG_RHTOPIC, t - 1858, s * 25000, 25000);
    else if (t < 2347) degSegS(d5,  200000, deg + DG_AFFIL,   t - 2249, s * 1000,  1000);
    else               degSegS(d6,  200000, deg + DG_RAFFIL,  t - 2347, s * 12500, 12500);
}

// ================= 3-phase exclusive scan =================
__global__ __launch_bounds__(256) void scan1(const int* __restrict__ deg,
                                             int* __restrict__ off,
                                             int* __restrict__ bsums, int n) {
    __shared__ int ts[256];
    const int tid = threadIdx.x;
    const int base = blockIdx.x * 1024 + tid * 4;
    int4 v = {0, 0, 0, 0};
    if (base < n) v = *(const int4*)(deg + base);
    int sum = v.x + v.y + v.z + v.w;
    ts[tid] = sum;
    __syncthreads();
    for (int o = 1; o < 256; o <<= 1) {
        int t = (tid >= o) ? ts[tid - o] : 0;
        __syncthreads();
        ts[tid] += t;
        __syncthreads();
    }
    int pre = ts[tid] - sum;
    if (base < n) {
        int4 e;
        e.x = pre;
        e.y = pre + v.x;
        e.z = pre + v.x + v.y;
        e.w = pre + v.x + v.y + v.z;
        *(int4*)(off + base) = e;
    }
    if (tid == 255) bsums[blockIdx.x] = ts[255];
}

__global__ __launch_bounds__(1024) void scan2(int* __restrict__ bsums, int nb) {
    __shared__ int ts[1024];
    const int tid = threadIdx.x;
    int v = (tid < nb) ? bsums[tid] : 0;
    ts[tid] = v;
    __syncthreads();
    for (int o = 1; o < 1024; o <<= 1) {
        int t = (tid >= o) ? ts[tid - o] : 0;
        __syncthreads();
        ts[tid] += t;
        __syncthreads();
    }
    if (tid < nb) bsums[tid] = ts[tid] - v;
}

__global__ __launch_bounds__(256) void scan3(int* __restrict__ off,
                                             int* __restrict__ cursor,
                                             const int* __restrict__ bsums,
                                             int n, int e_total) {
    const int tid = threadIdx.x;
    const int base = blockIdx.x * 1024 + tid * 4;
    const int bp = bsums[blockIdx.x];
    if (base < n) {
        int4 v = *(const int4*)(off + base);
        v.x += bp; v.y += bp; v.z += bp; v.w += bp;
        *(int4*)(off + base) = v;
        *(int4*)(cursor + base) = v;
    }
    if (blockIdx.x == 0 && tid == 0) off[n] = e_total;
}

// ============ XCD-sliced CSR fill ============
__device__ __forceinline__ void fillSegS(const int* __restrict__ src,
                                         const int* __restrict__ dst, int E,
                                         int* __restrict__ cursor,
                                         int* __restrict__ csr, int chunk,
                                         int lo, int wid) {
    const int base = chunk * 2048 + (int)threadIdx.x * 4;
    #pragma unroll
    for (int it = 0; it < 2; it++) {
        int i = base + it * 1024;
        if (i + 3 < E) {
            int4 d = *(const int4*)(dst + i);
            int4 sv = *(const int4*)(src + i);
            if ((unsigned)(d.x - lo) < (unsigned)wid) { int p = atomicAdd(&cursor[d.x], 1); csr[p] = sv.x; }
            if ((unsigned)(d.y - lo) < (unsigned)wid) { int p = atomicAdd(&cursor[d.y], 1); csr[p] = sv.y; }
            if ((unsigned)(d.z - lo) < (unsigned)wid) { int p = atomicAdd(&cursor[d.z], 1); csr[p] = sv.z; }
            if ((unsigned)(d.w - lo) < (unsigned)wid) { int p = atomicAdd(&cursor[d.w], 1); csr[p] = sv.w; }
        } else {
            for (int k = 0; k < 4; k++) {
                int ii = i + k;
                if (ii < E) {
                    int dd = dst[ii];
                    if ((unsigned)(dd - lo) < (unsigned)wid) {
                        int p = atomicAdd(&cursor[dd], 1);
                        csr[p] = src[ii];
                    }
                }
            }
        }
    }
}

__global__ __launch_bounds__(256) void fill_all(
    const int* s0, const int* d0, const int* s1, const int* d1,
    const int* s2, const int* d2, const int* s3, const int* d3,
    const int* s4, const int* d4, const int* s5, const int* d5,
    const int* s6, const int* d6,
    int* __restrict__ cursor, int* __restrict__ csr) {
    const int b = blockIdx.x;
    const int s = b & 7;         // slice -> XCD (round-robin dispatch)
    const int t = b >> 3;
    if      (t < 489)  fillSegS(s0, d0, 1000000, cursor + DG_WRITES,  csr, t,        s * 25000, 25000);
    else if (t < 978)  fillSegS(s1, d1, 1000000, cursor + DG_RWRITES, csr, t - 489,  s * 12500, 12500);
    else if (t < 1467) fillSegS(s2, d2, 1000000, cursor + DG_CITES,   csr, t - 978,  s * 25000, 25000);
    else if (t < 1858) fillSegS(s3, d3,  800000, cursor + DG_HTOPIC,  csr, t - 1467, s * 6250,  6250);
    else if (t < 2249) fillSegS(s4, d4,  800000, cursor + DG_RHTOPIC, csr, t - 1858, s * 25000, 25000);
    else if (t < 2347) fillSegS(s5, d5,  200000, cursor + DG_AFFIL,   csr, t - 2249, s * 1000,  1000);
    else               fillSegS(s6, d6,  200000, cursor + DG_RAFFIL,  csr, t - 2347, s * 12500, 12500);
}

// ================= W prep: 8 matrices f32[128][64] -> bf16 Wt[64][128] ========
__global__ __launch_bounds__(256) void prep_wt(const float* __restrict__ W7,
                                               const float* __restrict__ slw,
                                               short* __restrict__ Wt) {
    const int mat = blockIdx.x;
    const float* Ws = (mat < 7) ? (W7 + (size_t)mat * IN_F * OUT_F) : slw;
    short* Wo = Wt + (size_t)mat * IN_F * OUT_F;
    for (int i = threadIdx.x; i < IN_F * OUT_F; i += 256) {
        int n = i >> 7;
        int k = i & 127;
        Wo[i] = f2bf(Ws[k * OUT_F + n]);
    }
}

// ================= merged MFMA projection (64 rows/block, wave-owns-rows) =====
template <int R>
__device__ __forceinline__ void projBody(
    int blk, int nrows, const float* __restrict__ X,
    const short* __restrict__ wt0, const short* __restrict__ wt1,
    const short* __restrict__ wt2, const short* __restrict__ wtS,
    const float* __restrict__ bias,
    bf16* __restrict__ Y0, bf16* __restrict__ Y1, bf16* __restrict__ Y2,
    float* __restrict__ OutSelf) {
    const int tid = threadIdx.x;
    const int wave = tid >> 6;
    const int lane = tid & 63;
    const int m = lane & 15;
    const int quad = lane >> 4;
    const int rowBase = blk * 64 + wave * 16;
    if (rowBase >= nrows) return;                 // wave-uniform early out
    const bool full = (rowBase + 16 <= nrows);    // wave-uniform fast path

    int arow = rowBase + m;
    if (arow > nrows - 1) arow = nrows - 1;       // clamp load row

    short8 af[4];
    const float* xrow = X + (size_t)arow * IN_F + quad * 8;
    #pragma unroll
    for (int kb = 0; kb < 4; kb++) {
        float4 x0 = *(const float4*)(xrow + kb * 32);
        float4 x1 = *(const float4*)(xrow + kb * 32 + 4);
        short8 a;
        a[0] = f2bf(x0.x); a[1] = f2bf(x0.y); a[2] = f2bf(x0.z); a[3] = f2bf(x0.w);
        a[4] = f2bf(x1.x); a[5] = f2bf(x1.y); a[6] = f2bf(x1.z); a[7] = f2bf(x1.w);
        af[kb] = a;
    }

    const short* wts[3] = {wt0, wt1, wt2};
    bf16* Ys[3] = {Y0, Y1, Y2};

    #pragma unroll
    for (int r = 0; r < R; r++) {
        bf16* Yr = Ys[r];
        #pragma unroll
        for (int cb = 0; cb < 4; cb++) {
            const int ncol = cb * 16 + m;
            const short* wrow = wts[r] + (size_t)ncol * IN_F + quad * 8;
            f32x4 acc = {0.f, 0.f, 0.f, 0.f};
            #pragma unroll
            for (int kb = 0; kb < 4; kb++) {
                short8 bfr = *(const short8*)(wrow + kb * 32);
                acc = __builtin_amdgcn_mfma_f32_16x16x32_bf16(af[kb], bfr, acc, 0, 0, 0);
            }
            if (full) {
                #pragma unroll
                for (int reg = 0; reg < 4; reg++) {
                    int row = rowBase + quad * 4 + reg;
                    Yr[(size_t)row * OUT_F + ncol] = __float2bfloat16(acc[reg]);
                }
            } else {
                #pragma unroll
                for (int reg = 0; reg < 4; reg++) {
                    int row = rowBase + quad * 4 + reg;
                    if (row < nrows)
                        Yr[(size_t)row * OUT_F + ncol] = __float2bfloat16(acc[reg]);
                }
            }
        }
    }

    // self-loop + bias -> f32 out
    #pragma unroll
    for (int cb = 0; cb < 4; cb++) {
        const int ncol = cb * 16 + m;
        const short* wrow = wtS + (size_t)ncol * IN_F + quad * 8;
        f32x4 acc = {0.f, 0.f, 0.f, 0.f};
        #pragma unroll
        for (int kb = 0; kb < 4; kb++) {
            short8 bfr = *(const short8*)(wrow + kb * 32);
            acc = __builtin_amdgcn_mfma_f32_16x16x32_bf16(af[kb], bfr, acc, 0, 0, 0);
        }
        const float b = bias[ncol];
        if (full) {
            #pragma unroll
            for (int reg = 0; reg < 4; reg++) {
                int row = rowBase + quad * 4 + reg;
                OutSelf[(size_t)row * OUT_F + ncol] = acc[reg] + b;
            }
        } else {
            #pragma unroll
            for (int reg = 0; reg < 4; reg++) {
                int row = rowBase + quad * 4 + reg;
                if (row < nrows)
                    OutSelf[(size_t)row * OUT_F + ncol] = acc[reg] + b;
            }
        }
    }
}

// block ranges (64 rows/blk): paper 3125, author 1563, field 782, inst 125 -> 5595
__global__ __launch_bounds__(256) void proj_all(
    const float* __restrict__ x_author, const float* __restrict__ x_field,
    const float* __restrict__ x_inst,   const float* __restrict__ x_paper,
    const short* __restrict__ wt, const float* __restrict__ bias,
    bf16* __restrict__ y, float* __restrict__ out) {
    int b = blockIdx.x;
    if (b < 3125) {
        projBody<3>(b, N_PAPER, x_paper, wt + 1 * 8192, wt + 2 * 8192, wt + 3 * 8192, wt + 7 * 8192,
                    bias, y + YR_RWRITES * OUT_F, y + YR_CITES * OUT_F, y + YR_HTOPIC * OUT_F,
                    out + OUT_PAPER);
    } else if (b < 4688) {
        projBody<2>(b - 3125, N_AUTHOR, x_author, wt + 0 * 8192, wt + 5 * 8192, nullptr, wt + 7 * 8192,
                    bias, y + YR_WRITES * OUT_F, y + YR_AFFIL * OUT_F, nullptr,
                    out + OUT_AUTHOR);
    } else if (b < 5470) {
        projBody<1>(b - 4688, N_FIELD, x_field, wt + 4 * 8192, nullptr, nullptr, wt + 7 * 8192,
                    bias, y + YR_RHTOPIC * OUT_F, nullptr, nullptr,
                    out + OUT_FIELD);
    } else {
        projBody<1>(b - 5470, N_INST, x_inst, wt + 6 * 8192, nullptr, nullptr, wt + 7 * 8192,
                    bias, y + YR_RAFFIL * OUT_F, nullptr, nullptr,
                    out + OUT_INST);
    }
}

// ================= merged gather: 2 nodes/wave, batched first-iteration =======
// Latency-bound fix: all 2*NR first-iteration csr loads issue as one
// independent batch, then all 2*NR y-row loads (each depends only on its own
// csr word). One ~600-cycle chain per wave instead of up to 6 serialized ones.
// Consecutive nodes share off entries (E[p0]==S[p1]). Tail loop (deg>8) rare.
#define ACC8(racc, u, mk)                                                    \
    racc[0] += mk * bflo(u.x); racc[1] += mk * bfhi(u.x);                    \
    racc[2] += mk * bflo(u.y); racc[3] += mk * bfhi(u.y);                    \
    racc[4] += mk * bflo(u.z); racc[5] += mk * bfhi(u.z);                    \
    racc[6] += mk * bflo(u.w); racc[7] += mk * bfhi(u.w);

template <int NR>
__device__ __forceinline__ void gatherPair(
    int n0, int lane, const char* __restrict__ csrb,
    const int* __restrict__ off0, const char* __restrict__ y0,
    const int* __restrict__ off1, const char* __restrict__ y1,
    const int* __restrict__ off2, const char* __restrict__ y2,
    float* __restrict__ out) {
    const int g = lane >> 3;
    const int f = lane & 7;
    const unsigned foff = (unsigned)f << 4;
    const int* offs[3] = {off0, off1, off2};
    const char* ys[3] = {y0, y1, y2};

    int S[2][NR], E[2][NR];
    #pragma unroll
    for (int r = 0; r < NR; r++) {
        int a = offs[r][n0];
        int b = offs[r][n0 + 1];
        int c = offs[r][n0 + 2];
        S[0][r] = a; E[0][r] = b;
        S[1][r] = b; E[1][r] = c;
    }

    // batch 1: first-iteration csr loads (all independent)
    int C[2][NR];
    #pragma unroll
    for (int p = 0; p < 2; p++) {
        #pragma unroll
        for (int r = 0; r < NR; r++) {
            int i = S[p][r] + g;
            int ic = min(i, E[p][r] - 1);
            ic = (S[p][r] < E[p][r]) ? ic : 0;   // empty segment -> safe slot
            C[p][r] = *(const int*)(csrb + ((unsigned)ic << 2));
        }
    }

    // batch 2: first-iteration y-row loads (depend only on own csr word)
    uint4 U[2][NR];
    #pragma unroll
    for (int p = 0; p < 2; p++) {
        #pragma unroll
        for (int r = 0; r < NR; r++) {
            U[p][r] = *(const uint4*)(ys[r] + ((unsigned)C[p][r] << 7) + foff);
        }
    }

    float acc[2][8];
    #pragma unroll
    for (int p = 0; p < 2; p++)
        #pragma unroll
        for (int k = 0; k < 8; k++) acc[p][k] = 0.f;

    #pragma unroll
    for (int p = 0; p < 2; p++) {
        #pragma unroll
        for (int r = 0; r < NR; r++) {
            const int s = S[p][r];
            const int e = E[p][r];
            float racc[8] = {0.f, 0.f, 0.f, 0.f, 0.f, 0.f, 0.f, 0.f};
            {
                float mk = (s + g < e) ? 1.f : 0.f;
                uint4 u = U[p][r];
                ACC8(racc, u, mk)
            }
            // tail: deg > 8 (rare at mean 5.8)
            const char* __restrict__ yb = ys[r];
            for (int j = s + 8; j < e; j += 8) {
                int i = j + g;
                int ic = min(i, e - 1);
                int c2 = *(const int*)(csrb + ((unsigned)ic << 2));
                uint4 u2 = *(const uint4*)(yb + ((unsigned)c2 << 7) + foff);
                float m2 = (i < e) ? 1.f : 0.f;
                ACC8(racc, u2, m2)
            }
            float dg = (float)(e - s);
            float inv = __builtin_amdgcn_rcpf(dg > 1.f ? dg : 1.f);
            #pragma unroll
            for (int k = 0; k < 8; k++) acc[p][k] += racc[k] * inv;
        }
    }

    #pragma unroll
    for (int d = 8; d <= 32; d <<= 1) {
        #pragma unroll
        for (int p = 0; p < 2; p++)
            #pragma unroll
            for (int k = 0; k < 8; k++) acc[p][k] += __shfl_xor(acc[p][k], d, 64);
    }

    if (lane < 8) {
        #pragma unroll
        for (int p = 0; p < 2; p++) {
            float* orow = out + (size_t)(n0 + p) * OUT_F + f * 8;
            float4 c0 = *(float4*)orow;
            float4 c1 = *(float4*)(orow + 4);
            c0.x = fmaxf(c0.x + acc[p][0], 0.f); c0.y = fmaxf(c0.y + acc[p][1], 0.f);
            c0.z = fmaxf(c0.z + acc[p][2], 0.f); c0.w = fmaxf(c0.w + acc[p][3], 0.f);
            c1.x = fmaxf(c1.x + acc[p][4], 0.f); c1.y = fmaxf(c1.y + acc[p][5], 0.f);
            c1.z = fmaxf(c1.z + acc[p][6], 0.f); c1.w = fmaxf(c1.w + acc[p][7], 0.f);
            *(float4*)orow = c0;
            *(float4*)(orow + 4) = c1;
        }
    }
}

// block ranges (8 nodes/block, 2/wave): paper 25000, author 12500, field 6250, inst 1000
__global__ __launch_bounds__(256) void gather_all(
    const int* __restrict__ csr, const int* __restrict__ off,
    const bf16* __restrict__ y, float* __restrict__ out) {
    const int b = blockIdx.x;
    const int tid = threadIdx.x;
    const int lane = tid & 63;
    const int wv = tid >> 6;
    const char* csrb = (const char*)csr;
    if (b < 25000) {
        gatherPair<3>(b * 8 + wv * 2, lane, csrb,
                      off + DG_WRITES,  (const char*)(y + YR_WRITES * OUT_F),
                      off + DG_CITES,   (const char*)(y + YR_CITES * OUT_F),
                      off + DG_RHTOPIC, (const char*)(y + YR_RHTOPIC * OUT_F),
                      out + OUT_PAPER);
    } else if (b < 37500) {
        gatherPair<2>((b - 25000) * 8 + wv * 2, lane, csrb,
                      off + DG_RWRITES, (const char*)(y + YR_RWRITES * OUT_F),
                      off + DG_RAFFIL,  (const char*)(y + YR_RAFFIL * OUT_F),
                      nullptr, nullptr,
                      out + OUT_AUTHOR);
    } else if (b < 43750) {
        gatherPair<1>((b - 37500) * 8 + wv * 2, lane, csrb,
                      off + DG_HTOPIC, (const char*)(y + YR_HTOPIC * OUT_F),
                      nullptr, nullptr, nullptr, nullptr,
                      out + OUT_FIELD);
    } else {
        gatherPair<1>((b - 43750) * 8 + wv * 2, lane, csrb,
                      off + DG_AFFIL, (const char*)(y + YR_AFFIL * OUT_F),
                      nullptr, nullptr, nullptr, nullptr,
                      out + OUT_INST);
    }
}

extern "C" void kernel_launch(void* const* d_in, const int* in_sizes, int n_in,
                              void* d_out, int out_size, void* d_ws, size_t ws_size,
                              hipStream_t stream) {
    (void)in_sizes; (void)n_in; (void)ws_size; (void)out_size;

    const float* x_author = (const float*)d_in[0];
    const float* x_field  = (const float*)d_in[1];
    const float* x_inst   = (const float*)d_in[2];
    const float* x_paper  = (const float*)d_in[3];
    const float* weight   = (const float*)d_in[4];
    const float* slw      = (const float*)d_in[5];
    const float* bias     = (const float*)d_in[6];
    float* out = (float*)d_out;

    // ---- workspace layout ----
    char* w = (char*)d_ws;
    auto alignup = [](size_t v) { return (v + 127) & ~(size_t)127; };
    bf16* y  = (bf16*)w;              size_t o1 = alignup((size_t)N_NODES * OUT_F * sizeof(bf16));
    int* deg = (int*)(w + o1);        size_t o2 = o1 + alignup((size_t)N_NODES * sizeof(int));
    int* off = (int*)(w + o2);        size_t o3 = o2 + alignup(((size_t)N_NODES + 4) * sizeof(int));
    int* cursor = (int*)(w + o3);     size_t o4 = o3 + alignup((size_t)N_NODES * sizeof(int));
    int* csr = (int*)(w + o4);        size_t o5 = o4 + alignup((size_t)E_TOTAL * sizeof(int));
    int* bsums = (int*)(w + o5);      size_t o6 = o5 + alignup(2048 * sizeof(int));
    short* wt = (short*)(w + o6);

    const int* ws_p[7] = {(const int*)d_in[7],  (const int*)d_in[9],  (const int*)d_in[11],
                          (const int*)d_in[13], (const int*)d_in[15], (const int*)d_in[17],
                          (const int*)d_in[19]};
    const int* wd_p[7] = {(const int*)d_in[8],  (const int*)d_in[10], (const int*)d_in[12],
                          (const int*)d_in[14], (const int*)d_in[16], (const int*)d_in[18],
                          (const int*)d_in[20]};

    const int NBLK = (N_NODES + 1023) / 1024;   // 838
    const int SLICE_BLKS = 8 * 2445;            // 19560

    // 1) W transpose+cast (no deps)
    prep_wt<<<8, 256, 0, stream>>>(weight, slw, wt);

    // 2) degrees (XCD-sliced)
    hipMemsetAsync(deg, 0, (size_t)N_NODES * sizeof(int), stream);
    deg_all<<<SLICE_BLKS, 256, 0, stream>>>(wd_p[0], wd_p[1], wd_p[2], wd_p[3],
                                            wd_p[4], wd_p[5], wd_p[6], deg);

    // 3) scan -> off, cursor
    scan1<<<NBLK, 256, 0, stream>>>(deg, off, bsums, N_NODES);
    scan2<<<1, 1024, 0, stream>>>(bsums, NBLK);
    scan3<<<NBLK, 256, 0, stream>>>(off, cursor, bsums, N_NODES, E_TOTAL);

    // 4) CSR fill (XCD-sliced)
    fill_all<<<SLICE_BLKS, 256, 0, stream>>>(ws_p[0], wd_p[0], ws_p[1], wd_p[1],
                                             ws_p[2], wd_p[2], ws_p[3], wd_p[3],
                                             ws_p[4], wd_p[4], ws_p[5], wd_p[5],
                                             ws_p[6], wd_p[6], cursor, csr);

    // 5) fused MFMA projections + self-loop init (64 rows/block)
    proj_all<<<5595, 256, 0, stream>>>(x_author, x_field, x_inst, x_paper,
                                       wt, bias, y, out);

    // 6) fused gather + norm + selfloop-add + relu (2 nodes/wave)
    gather_all<<<44750, 256, 0, stream>>>(csr, off, y, out);
}